// Round 8
// baseline (298.639 us; speedup 1.0000x reference)
//
#include <hip/hip_runtime.h>

#define N_NODES 50000
#define DIM     128
#define N_EDGES 800000
#define N_LABEL 200000

// bucket partition: bucket = dst >> 7 (128 nodes/bucket), fixed capacity slots
#define NBUCK 391            // ceil(50000/128)
#define CAP   4096           // slots per bucket (mean fill ~2046, 40-sigma margin)
#define NPBLK 250            // partition blocks
#define CHUNK 3200           // edges per partition block

typedef __attribute__((ext_vector_type(8)))  short short8;    // 8 bf16 (4 VGPRs)
typedef __attribute__((ext_vector_type(16))) float floatx16;  // 32x32 MFMA acc

// split fp32 into bf16 hi + bf16 lo (x ~= hi + lo, rel err ~2^-17), RNE both
__device__ inline void f32_to_bf16x2(float x, unsigned short& hi, unsigned short& lo) {
    unsigned u  = __float_as_uint(x);
    unsigned rh = (u + 0x7FFFu + ((u >> 16) & 1u)) >> 16;
    hi = (unsigned short)rh;
    float hif = __uint_as_float(rh << 16);
    float r = x - hif;
    unsigned ul = __float_as_uint(r);
    unsigned rl = (ul + 0x7FFFu + ((ul >> 16) & 1u)) >> 16;
    lo = (unsigned short)rl;
}

__device__ inline unsigned short f32_to_bf16(float x) {
    unsigned u = __float_as_uint(x);
    return (unsigned short)((u + 0x7FFFu + ((u >> 16) & 1u)) >> 16);
}

__device__ inline unsigned pack_bf16x2(float a, float b) {
    return (unsigned)f32_to_bf16(a) | ((unsigned)f32_to_bf16(b) << 16);
}

__device__ inline float bf_lo(unsigned u) { return __uint_as_float(u << 16); }
__device__ inline float bf_hi(unsigned u) { return __uint_as_float(u & 0xFFFF0000u); }

// fused: blocks [0,6250) build h0 (fp32 + bf16); [6250,6282) swizzle W; 6282 zeroes bcount
__global__ __launch_bounds__(256)
void build_h0_wf(const int* __restrict__ n_id,
                 const float* __restrict__ emb,
                 const float* __restrict__ xs,
                 float* __restrict__ h0,
                 unsigned* __restrict__ hb0,
                 const float* __restrict__ W1l, const float* __restrict__ W1r,
                 const float* __restrict__ W2l, const float* __restrict__ W2r,
                 unsigned short* __restrict__ WfH, unsigned short* __restrict__ WfL,
                 int* __restrict__ bcount) {
    if (blockIdx.x < 6250) {
        int t = blockIdx.x * 256 + threadIdx.x;     // < N_NODES*32 exactly
        int i = t >> 5, c = t & 31;
        float4 v;
        if (c < 16) {
            int nid = n_id[i];
            v = ((const float4*)emb)[nid * 16 + c];
        } else {
            v = ((const float4*)xs)[i * 16 + (c - 16)];
        }
        ((float4*)h0)[i * 32 + c] = v;
        uint2 p;
        p.x = pack_bf16x2(v.x, v.y);
        p.y = pack_bf16x2(v.z, v.w);
        ((uint2*)hb0)[i * 32 + c] = p;
    } else if (blockIdx.x < 6282) {
        int t = (blockIdx.x - 6250) * 256 + threadIdx.x;   // 8192 chunks
        if (t >= 8192) return;
        int L  = t & 63;
        int nt = (t >> 6) & 3;
        int ks = (t >> 8) & 7;
        int p  = (t >> 11) & 1;
        int ly = t >> 12;
        const float* Ws[4] = {W1l, W1r, W2l, W2r};
        const float* W = Ws[ly * 2 + p];
        int n = nt * 32 + (L & 31);
        int kbase = ks * 16 + (L >> 5) * 8;
        short8 hv, lv;
#pragma unroll
        for (int j = 0; j < 8; ++j) {
            unsigned short hh, ll;
            f32_to_bf16x2(W[(kbase + j) * DIM + n], hh, ll);
            hv[j] = (short)hh;
            lv[j] = (short)ll;
        }
        *(short8*)(WfH + (size_t)t * 8) = hv;
        *(short8*)(WfL + (size_t)t * 8) = lv;
    } else {
        for (int i = threadIdx.x; i < NBUCK; i += 256) bcount[i] = 0;
    }
}

// fused hist + range-reserve + grouped scatter (no global scan)
__global__ __launch_bounds__(256)
void part_scatter(const int* __restrict__ src, const int* __restrict__ dst,
                  int* __restrict__ bcount, uint2* __restrict__ part) {
    __shared__ int hist[NBUCK];      // pass1: counts; pass2: write cursors
    int t = threadIdx.x;
    for (int i = t; i < NBUCK; i += 256) hist[i] = 0;
    __syncthreads();
    int base = blockIdx.x * CHUNK;
    for (int e = base + t; e < base + CHUNK; e += 256)
        atomicAdd(&hist[dst[e] >> 7], 1);
    __syncthreads();
    for (int i = t; i < NBUCK; i += 256) {
        int c = hist[i];
        hist[i] = c ? atomicAdd(&bcount[i], c) : 0;   // reserve [base, base+c)
    }
    __syncthreads();
    for (int e = base + t; e < base + CHUNK; e += 256) {
        int d = dst[e];
        int bk = d >> 7;
        int pos = atomicAdd(&hist[bk], 1);
        part[bk * CAP + pos] = make_uint2((unsigned)src[e], (unsigned)(d & 127));
    }
}

// per-bucket: local deg + LDS scan -> nbeg/nend, then localized csr scatter
__global__ __launch_bounds__(256)
void bucket_csr(const uint2* __restrict__ part, const int* __restrict__ bcount,
                int* __restrict__ nbeg, int* __restrict__ nend, int* __restrict__ csr) {
    __shared__ int ldeg[128];
    __shared__ int lcur[128];
    __shared__ int w0s;
    int bk = blockIdx.x;
    int t = threadIdx.x;
    int cnt = bcount[bk];
    int base = bk * CAP;
    if (t < 128) ldeg[t] = 0;
    __syncthreads();
    for (int e = t; e < cnt; e += 256)
        atomicAdd(&ldeg[part[base + e].y], 1);
    __syncthreads();
    int lane = t & 63, wid = t >> 6;
    int v = (t < 128) ? ldeg[t] : 0;
    int s = v;
#pragma unroll
    for (int off = 1; off < 64; off <<= 1) {
        int u = __shfl_up(s, off, 64);
        if (lane >= off) s += u;
    }
    if (t == 63) w0s = s;
    __syncthreads();
    if (t < 128) {
        int excl = s - v + ((wid == 1) ? w0s : 0);
        int node = bk * 128 + t;
        int b0 = base + excl;
        if (node < N_NODES) { nbeg[node] = b0; nend[node] = b0 + v; }
        lcur[t] = b0;
    }
    __syncthreads();
    for (int e = t; e < cnt; e += 256) {
        uint2 p = part[base + e];
        int pos = atomicAdd(&lcur[p.y], 1);
        csr[pos] = (int)p.x;
    }
}

// Fused SAGE layer: block = 64 nodes, 256 threads (4 waves).
// Phase 1: each wave gather-means 16 nodes (bf16 h gather) into LDS.
// Phase 2: out = relu?( aggLDS@Wl + h@Wr + b ) via 32x32x16 bf16 MFMA hi/lo.
#define ALD 132    // LDS leading dim (floats): stride%32=4 -> 4-way on b128 reads

template <int RELU, int WRITE_BF16>
__global__ __launch_bounds__(256)
void sage_layer(const int* __restrict__ nbeg, const int* __restrict__ nend,
                const int* __restrict__ csr_src,
                const unsigned* __restrict__ hb,    // bf16-packed h (gather src)
                const float* __restrict__ h,        // fp32 h (self term)
                const unsigned short* __restrict__ WfH,
                const unsigned short* __restrict__ WfL,
                const float* __restrict__ b,
                float* __restrict__ out,
                unsigned short* __restrict__ outb) {
    __shared__ float aggs[64][ALD];
    int tid  = threadIdx.x;
    int lane = tid & 63;
    int w    = tid >> 6;

    // ---- phase 1: aggregate 16 nodes per wave into LDS ----
    int nodebase = blockIdx.x * 64 + w * 16;
    for (int i = 0; i < 16; ++i) {
        int node = nodebase + i;
        int beg = 0, end = 0;
        if (node < N_NODES) { beg = nbeg[node]; end = nend[node]; }
        float ax0 = 0.f, ay0 = 0.f, ax1 = 0.f, ay1 = 0.f;
        for (int bb = beg; bb < end; bb += 64) {
            int cnt = min(64, end - bb);
            int idx = (bb + lane < end) ? csr_src[bb + lane] : 0;
            int j = 0;
            for (; j + 4 <= cnt; j += 4) {
                int s0 = __shfl(idx, j,     64);
                int s1 = __shfl(idx, j + 1, 64);
                int s2 = __shfl(idx, j + 2, 64);
                int s3 = __shfl(idx, j + 3, 64);
                unsigned v0 = hb[s0 * 64 + lane];
                unsigned v1 = hb[s1 * 64 + lane];
                unsigned v2 = hb[s2 * 64 + lane];
                unsigned v3 = hb[s3 * 64 + lane];
                ax0 += bf_lo(v0); ay0 += bf_hi(v0);
                ax1 += bf_lo(v1); ay1 += bf_hi(v1);
                ax0 += bf_lo(v2); ay0 += bf_hi(v2);
                ax1 += bf_lo(v3); ay1 += bf_hi(v3);
            }
            for (; j < cnt; ++j) {
                int s = __shfl(idx, j, 64);
                unsigned v = hb[s * 64 + lane];
                ax0 += bf_lo(v); ay0 += bf_hi(v);
            }
        }
        float rd = 1.0f / fmaxf((float)(end - beg), 1.0f);
        aggs[w * 16 + i][lane * 2]     = (ax0 + ax1) * rd;
        aggs[w * 16 + i][lane * 2 + 1] = (ay0 + ay1) * rd;
    }
    __syncthreads();

    // ---- phase 2: MFMA linear ----
    int row0 = blockIdx.x * 64 + (w & 1) * 32;
    int colhalf = w >> 1;
    int nt0 = colhalf * 2;
    int mloc = (w & 1) * 32 + (lane & 31);       // LDS row for A-agg
    int mc   = min(row0 + (lane & 31), N_NODES - 1);
    int kh = lane >> 5;

    floatx16 acc0, acc1;
#pragma unroll
    for (int i = 0; i < 16; ++i) { acc0[i] = 0.f; acc1[i] = 0.f; }

    const float* hrow = h + (size_t)mc * DIM + kh * 8;
    for (int p = 0; p < 2; ++p) {
#pragma unroll
        for (int ks = 0; ks < 8; ++ks) {
            float4 a0, a1;
            if (p == 0) {
                a0 = *(const float4*)&aggs[mloc][ks * 16 + kh * 8];
                a1 = *(const float4*)&aggs[mloc][ks * 16 + kh * 8 + 4];
            } else {
                a0 = *(const float4*)(hrow + ks * 16);
                a1 = *(const float4*)(hrow + ks * 16 + 4);
            }
            float av[8] = {a0.x, a0.y, a0.z, a0.w, a1.x, a1.y, a1.z, a1.w};
            short8 ah, al;
#pragma unroll
            for (int j = 0; j < 8; ++j) {
                unsigned short hh, ll;
                f32_to_bf16x2(av[j], hh, ll);
                ah[j] = (short)hh;
                al[j] = (short)ll;
            }
            int cbase = ((p * 8 + ks) * 4 + nt0) * 64 + lane;
            short8 bh0 = *(const short8*)(WfH + (size_t)cbase * 8);
            short8 bl0 = *(const short8*)(WfL + (size_t)cbase * 8);
            short8 bh1 = *(const short8*)(WfH + (size_t)(cbase + 64) * 8);
            short8 bl1 = *(const short8*)(WfL + (size_t)(cbase + 64) * 8);
            acc0 = __builtin_amdgcn_mfma_f32_32x32x16_bf16(ah, bh0, acc0, 0, 0, 0);
            acc0 = __builtin_amdgcn_mfma_f32_32x32x16_bf16(ah, bl0, acc0, 0, 0, 0);
            acc0 = __builtin_amdgcn_mfma_f32_32x32x16_bf16(al, bh0, acc0, 0, 0, 0);
            acc1 = __builtin_amdgcn_mfma_f32_32x32x16_bf16(ah, bh1, acc1, 0, 0, 0);
            acc1 = __builtin_amdgcn_mfma_f32_32x32x16_bf16(ah, bl1, acc1, 0, 0, 0);
            acc1 = __builtin_amdgcn_mfma_f32_32x32x16_bf16(al, bh1, acc1, 0, 0, 0);
        }
    }

    int col0 = colhalf * 64 + (lane & 31);
    float b0 = b[col0], b1 = b[col0 + 32];
#pragma unroll
    for (int reg = 0; reg < 16; ++reg) {
        int rloc = (reg & 3) + 8 * (reg >> 2) + 4 * kh;   // C/D row map (m74/m101)
        int rowg = row0 + rloc;
        if (rowg < N_NODES) {
            float v0 = acc0[reg] + b0;
            float v1 = acc1[reg] + b1;
            if (RELU) { v0 = fmaxf(v0, 0.f); v1 = fmaxf(v1, 0.f); }
            out[(size_t)rowg * DIM + col0]      = v0;
            out[(size_t)rowg * DIM + col0 + 32] = v1;
            if (WRITE_BF16) {
                outb[(size_t)rowg * DIM + col0]      = f32_to_bf16(v0);
                outb[(size_t)rowg * DIM + col0 + 32] = f32_to_bf16(v1);
            }
        }
    }
}

// logits from fp32 h2; 32 threads/edge + shfl reduce
__global__ void edge_dot(const int* __restrict__ esrc, const int* __restrict__ edst,
                         const float* __restrict__ h2, float* __restrict__ out) {
    int t = blockIdx.x * blockDim.x + threadIdx.x;
    int e = t >> 5, c = t & 31;
    if (e >= N_LABEL) return;
    float4 a  = ((const float4*)h2)[esrc[e] * 32 + c];
    float4 bb = ((const float4*)h2)[edst[e] * 32 + c];
    float p = a.x * bb.x + a.y * bb.y + a.z * bb.z + a.w * bb.w;
#pragma unroll
    for (int off = 16; off; off >>= 1) p += __shfl_down(p, off, 32);
    if (c == 0) out[e] = p;
}

extern "C" void kernel_launch(void* const* d_in, const int* in_sizes, int n_in,
                              void* d_out, int out_size, void* d_ws, size_t ws_size,
                              hipStream_t stream) {
    const int*   n_id     = (const int*)d_in[0];
    const float* x_struct = (const float*)d_in[1];
    const int*   e_idx    = (const int*)d_in[2];   // [2, N_EDGES]
    const int*   eli      = (const int*)d_in[3];   // [2, N_LABEL]
    const float* emb      = (const float*)d_in[4];
    const float* W1l      = (const float*)d_in[5];
    const float* W1r      = (const float*)d_in[6];
    const float* b1       = (const float*)d_in[7];
    const float* W2l      = (const float*)d_in[8];
    const float* W2r      = (const float*)d_in[9];
    const float* b2       = (const float*)d_in[10];
    float* out = (float*)d_out;

    const int* src = e_idx;
    const int* dst = e_idx + N_EDGES;

    const size_t HN = (size_t)N_NODES * DIM;       // 6.4M floats
    float* h0     = (float*)d_ws;
    float* h1     = h0 + HN;
    unsigned* hb0 = (unsigned*)(h1 + HN);          // N_NODES*64 uints
    unsigned* hb1 = hb0 + (size_t)N_NODES * 64;
    int*   nbeg   = (int*)(hb1 + (size_t)N_NODES * 64);
    int*   nend   = nbeg + N_NODES;
    int*   bcount = nend + N_NODES;                // NBUCK
    int*   csr    = bcount + NBUCK;                // NBUCK*CAP
    uintptr_t pa  = ((uintptr_t)(csr + NBUCK * CAP) + 15) & ~(uintptr_t)15;
    uint2* part   = (uint2*)pa;                    // NBUCK*CAP (src, dst&127)
    unsigned short* WfH = (unsigned short*)(part + NBUCK * CAP);  // 2*32768
    unsigned short* WfL = WfH + 2 * 32768;
    float* h2     = h0;                            // h0 dead after layer 1

    build_h0_wf<<<6283, 256, 0, stream>>>(n_id, emb, x_struct, h0, hb0,
                                          W1l, W1r, W2l, W2r, WfH, WfL, bcount);

    // CSR build: 2 kernels, fixed-capacity buckets, no global scan
    part_scatter<<<NPBLK, 256, 0, stream>>>(src, dst, bcount, part);
    bucket_csr<<<NBUCK, 256, 0, stream>>>(part, bcount, nbeg, nend, csr);

    // layer 1 (fused aggregate+linear): h1 fp32 + hb1 bf16
    sage_layer<1, 1><<<(N_NODES + 63) / 64, 256, 0, stream>>>(
        nbeg, nend, csr, hb0, h0, WfH, WfL, b1, h1, (unsigned short*)hb1);

    // layer 2: h2 fp32 (edge_dot reads fp32 for accuracy margin)
    sage_layer<0, 0><<<(N_NODES + 63) / 64, 256, 0, stream>>>(
        nbeg, nend, csr, hb1, h1, WfH + 32768, WfL + 32768, b2, h2, nullptr);

    edge_dot<<<(N_LABEL * 32 + 255) / 256, 256, 0, stream>>>(eli, eli + N_LABEL, h2, out);
}

// Round 9
// 267.209 us; speedup vs baseline: 1.1176x; 1.1176x over previous
//
#include <hip/hip_runtime.h>

#define N_NODES 50000
#define DIM     128
#define N_EDGES 800000
#define N_LABEL 200000

// bucket partition: bucket = dst >> 7 (128 nodes/bucket), fixed capacity slots
#define NBUCK 391            // ceil(50000/128)
#define CAP   4096           // slots per bucket (mean fill ~2046, 40-sigma margin)
#define NPBLK 250            // partition blocks
#define CHUNK 3200           // edges per partition block

typedef __attribute__((ext_vector_type(8)))  short short8;    // 8 bf16 (4 VGPRs)
typedef __attribute__((ext_vector_type(16))) float floatx16;  // 32x32 MFMA acc

// split fp32 into bf16 hi + bf16 lo (x ~= hi + lo, rel err ~2^-17), RNE both
__device__ inline void f32_to_bf16x2(float x, unsigned short& hi, unsigned short& lo) {
    unsigned u  = __float_as_uint(x);
    unsigned rh = (u + 0x7FFFu + ((u >> 16) & 1u)) >> 16;
    hi = (unsigned short)rh;
    float hif = __uint_as_float(rh << 16);
    float r = x - hif;
    unsigned ul = __float_as_uint(r);
    unsigned rl = (ul + 0x7FFFu + ((ul >> 16) & 1u)) >> 16;
    lo = (unsigned short)rl;
}

__device__ inline unsigned short f32_to_bf16(float x) {
    unsigned u = __float_as_uint(x);
    return (unsigned short)((u + 0x7FFFu + ((u >> 16) & 1u)) >> 16);
}

__device__ inline unsigned pack_bf16x2(float a, float b) {
    return (unsigned)f32_to_bf16(a) | ((unsigned)f32_to_bf16(b) << 16);
}

__device__ inline float bf_lo(unsigned u) { return __uint_as_float(u << 16); }
__device__ inline float bf_hi(unsigned u) { return __uint_as_float(u & 0xFFFF0000u); }

// fused: blocks [0,6250) build h0 (fp32 + bf16); [6250,6282) swizzle W; 6282 zeroes bcount
__global__ __launch_bounds__(256)
void build_h0_wf(const int* __restrict__ n_id,
                 const float* __restrict__ emb,
                 const float* __restrict__ xs,
                 float* __restrict__ h0,
                 unsigned* __restrict__ hb0,
                 const float* __restrict__ W1l, const float* __restrict__ W1r,
                 const float* __restrict__ W2l, const float* __restrict__ W2r,
                 unsigned short* __restrict__ WfH, unsigned short* __restrict__ WfL,
                 int* __restrict__ bcount) {
    if (blockIdx.x < 6250) {
        int t = blockIdx.x * 256 + threadIdx.x;     // < N_NODES*32 exactly
        int i = t >> 5, c = t & 31;
        float4 v;
        if (c < 16) {
            int nid = n_id[i];
            v = ((const float4*)emb)[nid * 16 + c];
        } else {
            v = ((const float4*)xs)[i * 16 + (c - 16)];
        }
        ((float4*)h0)[i * 32 + c] = v;
        uint2 p;
        p.x = pack_bf16x2(v.x, v.y);
        p.y = pack_bf16x2(v.z, v.w);
        ((uint2*)hb0)[i * 32 + c] = p;
    } else if (blockIdx.x < 6282) {
        int t = (blockIdx.x - 6250) * 256 + threadIdx.x;   // 8192 chunks
        if (t >= 8192) return;
        int L  = t & 63;
        int nt = (t >> 6) & 3;
        int ks = (t >> 8) & 7;
        int p  = (t >> 11) & 1;
        int ly = t >> 12;
        const float* Ws[4] = {W1l, W1r, W2l, W2r};
        const float* W = Ws[ly * 2 + p];
        int n = nt * 32 + (L & 31);
        int kbase = ks * 16 + (L >> 5) * 8;
        short8 hv, lv;
#pragma unroll
        for (int j = 0; j < 8; ++j) {
            unsigned short hh, ll;
            f32_to_bf16x2(W[(kbase + j) * DIM + n], hh, ll);
            hv[j] = (short)hh;
            lv[j] = (short)ll;
        }
        *(short8*)(WfH + (size_t)t * 8) = hv;
        *(short8*)(WfL + (size_t)t * 8) = lv;
    } else {
        for (int i = threadIdx.x; i < NBUCK; i += 256) bcount[i] = 0;
    }
}

// fused hist + range-reserve + grouped scatter (no global scan)
__global__ __launch_bounds__(256)
void part_scatter(const int* __restrict__ src, const int* __restrict__ dst,
                  int* __restrict__ bcount, uint2* __restrict__ part) {
    __shared__ int hist[NBUCK];      // pass1: counts; pass2: write cursors
    int t = threadIdx.x;
    for (int i = t; i < NBUCK; i += 256) hist[i] = 0;
    __syncthreads();
    int base = blockIdx.x * CHUNK;
    for (int e = base + t; e < base + CHUNK; e += 256)
        atomicAdd(&hist[dst[e] >> 7], 1);
    __syncthreads();
    for (int i = t; i < NBUCK; i += 256) {
        int c = hist[i];
        hist[i] = c ? atomicAdd(&bcount[i], c) : 0;   // reserve [base, base+c)
    }
    __syncthreads();
    for (int e = base + t; e < base + CHUNK; e += 256) {
        int d = dst[e];
        int bk = d >> 7;
        int pos = atomicAdd(&hist[bk], 1);
        part[bk * CAP + pos] = make_uint2((unsigned)src[e], (unsigned)(d & 127));
    }
}

// per-bucket: local deg + LDS scan -> nbeg/nend, then localized csr scatter
__global__ __launch_bounds__(256)
void bucket_csr(const uint2* __restrict__ part, const int* __restrict__ bcount,
                int* __restrict__ nbeg, int* __restrict__ nend, int* __restrict__ csr) {
    __shared__ int ldeg[128];
    __shared__ int lcur[128];
    __shared__ int w0s;
    int bk = blockIdx.x;
    int t = threadIdx.x;
    int cnt = bcount[bk];
    int base = bk * CAP;
    if (t < 128) ldeg[t] = 0;
    __syncthreads();
    for (int e = t; e < cnt; e += 256)
        atomicAdd(&ldeg[part[base + e].y], 1);
    __syncthreads();
    int lane = t & 63, wid = t >> 6;
    int v = (t < 128) ? ldeg[t] : 0;
    int s = v;
#pragma unroll
    for (int off = 1; off < 64; off <<= 1) {
        int u = __shfl_up(s, off, 64);
        if (lane >= off) s += u;
    }
    if (t == 63) w0s = s;
    __syncthreads();
    if (t < 128) {
        int excl = s - v + ((wid == 1) ? w0s : 0);
        int node = bk * 128 + t;
        int b0 = base + excl;
        if (node < N_NODES) { nbeg[node] = b0; nend[node] = b0 + v; }
        lcur[t] = b0;
    }
    __syncthreads();
    for (int e = t; e < cnt; e += 256) {
        uint2 p = part[base + e];
        int pos = atomicAdd(&lcur[p.y], 1);
        csr[pos] = (int)p.x;
    }
}

// gather-mean from packed bf16 h; one wave per node, lane holds 2 elems (1 uint).
// Inner loop batched x4 for memory-level parallelism. Output: packed bf16 agg.
__global__ void aggregate_bf16(const int* __restrict__ nbeg, const int* __restrict__ nend,
                               const int* __restrict__ csr_src,
                               const unsigned* __restrict__ hb,
                               unsigned* __restrict__ aggb) {
    int wv   = (blockIdx.x * blockDim.x + threadIdx.x) >> 6;
    int lane = threadIdx.x & 63;
    if (wv >= N_NODES) return;
    int beg = nbeg[wv], end = nend[wv];
    float ax0 = 0.f, ay0 = 0.f, ax1 = 0.f, ay1 = 0.f;
    for (int b = beg; b < end; b += 64) {
        int cnt = min(64, end - b);
        int idx = (b + lane < end) ? csr_src[b + lane] : 0;
        int j = 0;
        for (; j + 4 <= cnt; j += 4) {
            int s0 = __shfl(idx, j,     64);
            int s1 = __shfl(idx, j + 1, 64);
            int s2 = __shfl(idx, j + 2, 64);
            int s3 = __shfl(idx, j + 3, 64);
            unsigned v0 = hb[s0 * 64 + lane];
            unsigned v1 = hb[s1 * 64 + lane];
            unsigned v2 = hb[s2 * 64 + lane];
            unsigned v3 = hb[s3 * 64 + lane];
            ax0 += bf_lo(v0); ay0 += bf_hi(v0);
            ax1 += bf_lo(v1); ay1 += bf_hi(v1);
            ax0 += bf_lo(v2); ay0 += bf_hi(v2);
            ax1 += bf_lo(v3); ay1 += bf_hi(v3);
        }
        for (; j < cnt; ++j) {
            int s = __shfl(idx, j, 64);
            unsigned v = hb[s * 64 + lane];
            ax0 += bf_lo(v); ay0 += bf_hi(v);
        }
    }
    float rd = 1.0f / fmaxf((float)(end - beg), 1.0f);
    aggb[wv * 64 + lane] = pack_bf16x2((ax0 + ax1) * rd, (ay0 + ay1) * rd);
}

// out = relu?( aggb@Wl + h@Wr + b ); agg A is bf16-exact (2 MFMAs), h is fp32 hi/lo (3 MFMAs).
template <int RELU, int WRITE_BF16>
__global__ __launch_bounds__(256)
void linear_mfma(const unsigned* __restrict__ aggb,
                 const float* __restrict__ h,
                 const unsigned short* __restrict__ WfH,
                 const unsigned short* __restrict__ WfL,
                 const float* __restrict__ b,
                 float* __restrict__ out,
                 unsigned short* __restrict__ outb) {
    int tid  = threadIdx.x;
    int lane = tid & 63;
    int w    = tid >> 6;
    int row0 = blockIdx.x * 64 + (w & 1) * 32;
    int colhalf = w >> 1;
    int nt0 = colhalf * 2;
    int mc = min(row0 + (lane & 31), N_NODES - 1);
    int kh = lane >> 5;

    floatx16 acc0, acc1;
#pragma unroll
    for (int i = 0; i < 16; ++i) { acc0[i] = 0.f; acc1[i] = 0.f; }

    // phase 0: agg term — A already bf16 (exact), features ks*16+kh*8..+7 = uints ks*8+kh*4..+3
    const unsigned* arow = aggb + (size_t)mc * 64 + kh * 4;
#pragma unroll
    for (int ks = 0; ks < 8; ++ks) {
        short8 ah = *(const short8*)(arow + ks * 8);
        int cbase = (ks * 4 + nt0) * 64 + lane;
        short8 bh0 = *(const short8*)(WfH + (size_t)cbase * 8);
        short8 bl0 = *(const short8*)(WfL + (size_t)cbase * 8);
        short8 bh1 = *(const short8*)(WfH + (size_t)(cbase + 64) * 8);
        short8 bl1 = *(const short8*)(WfL + (size_t)(cbase + 64) * 8);
        acc0 = __builtin_amdgcn_mfma_f32_32x32x16_bf16(ah, bh0, acc0, 0, 0, 0);
        acc0 = __builtin_amdgcn_mfma_f32_32x32x16_bf16(ah, bl0, acc0, 0, 0, 0);
        acc1 = __builtin_amdgcn_mfma_f32_32x32x16_bf16(ah, bh1, acc1, 0, 0, 0);
        acc1 = __builtin_amdgcn_mfma_f32_32x32x16_bf16(ah, bl1, acc1, 0, 0, 0);
    }

    // phase 1: self term — fp32 h, hi/lo split (3 MFMAs per col-half)
    const float* hrow = h + (size_t)mc * DIM + kh * 8;
#pragma unroll
    for (int ks = 0; ks < 8; ++ks) {
        float4 a0 = *(const float4*)(hrow + ks * 16);
        float4 a1 = *(const float4*)(hrow + ks * 16 + 4);
        float av[8] = {a0.x, a0.y, a0.z, a0.w, a1.x, a1.y, a1.z, a1.w};
        short8 ah, al;
#pragma unroll
        for (int j = 0; j < 8; ++j) {
            unsigned short hh, ll;
            f32_to_bf16x2(av[j], hh, ll);
            ah[j] = (short)hh;
            al[j] = (short)ll;
        }
        int cbase = ((8 + ks) * 4 + nt0) * 64 + lane;
        short8 bh0 = *(const short8*)(WfH + (size_t)cbase * 8);
        short8 bl0 = *(const short8*)(WfL + (size_t)cbase * 8);
        short8 bh1 = *(const short8*)(WfH + (size_t)(cbase + 64) * 8);
        short8 bl1 = *(const short8*)(WfL + (size_t)(cbase + 64) * 8);
        acc0 = __builtin_amdgcn_mfma_f32_32x32x16_bf16(ah, bh0, acc0, 0, 0, 0);
        acc0 = __builtin_amdgcn_mfma_f32_32x32x16_bf16(ah, bl0, acc0, 0, 0, 0);
        acc0 = __builtin_amdgcn_mfma_f32_32x32x16_bf16(al, bh0, acc0, 0, 0, 0);
        acc1 = __builtin_amdgcn_mfma_f32_32x32x16_bf16(ah, bh1, acc1, 0, 0, 0);
        acc1 = __builtin_amdgcn_mfma_f32_32x32x16_bf16(ah, bl1, acc1, 0, 0, 0);
        acc1 = __builtin_amdgcn_mfma_f32_32x32x16_bf16(al, bh1, acc1, 0, 0, 0);
    }

    int col0 = colhalf * 64 + (lane & 31);
    float b0 = b[col0], b1 = b[col0 + 32];
#pragma unroll
    for (int reg = 0; reg < 16; ++reg) {
        int rloc = (reg & 3) + 8 * (reg >> 2) + 4 * kh;   // C/D row map (m74/m101)
        int rowg = row0 + rloc;
        if (rowg < N_NODES) {
            float v0 = acc0[reg] + b0;
            float v1 = acc1[reg] + b1;
            if (RELU) { v0 = fmaxf(v0, 0.f); v1 = fmaxf(v1, 0.f); }
            out[(size_t)rowg * DIM + col0]      = v0;
            out[(size_t)rowg * DIM + col0 + 32] = v1;
            if (WRITE_BF16) {
                outb[(size_t)rowg * DIM + col0]      = f32_to_bf16(v0);
                outb[(size_t)rowg * DIM + col0 + 32] = f32_to_bf16(v1);
            }
        }
    }
}

// logits from fp32 h2; 32 threads/edge + shfl reduce
__global__ void edge_dot(const int* __restrict__ esrc, const int* __restrict__ edst,
                         const float* __restrict__ h2, float* __restrict__ out) {
    int t = blockIdx.x * blockDim.x + threadIdx.x;
    int e = t >> 5, c = t & 31;
    if (e >= N_LABEL) return;
    float4 a  = ((const float4*)h2)[esrc[e] * 32 + c];
    float4 bb = ((const float4*)h2)[edst[e] * 32 + c];
    float p = a.x * bb.x + a.y * bb.y + a.z * bb.z + a.w * bb.w;
#pragma unroll
    for (int off = 16; off; off >>= 1) p += __shfl_down(p, off, 32);
    if (c == 0) out[e] = p;
}

extern "C" void kernel_launch(void* const* d_in, const int* in_sizes, int n_in,
                              void* d_out, int out_size, void* d_ws, size_t ws_size,
                              hipStream_t stream) {
    const int*   n_id     = (const int*)d_in[0];
    const float* x_struct = (const float*)d_in[1];
    const int*   e_idx    = (const int*)d_in[2];   // [2, N_EDGES]
    const int*   eli      = (const int*)d_in[3];   // [2, N_LABEL]
    const float* emb      = (const float*)d_in[4];
    const float* W1l      = (const float*)d_in[5];
    const float* W1r      = (const float*)d_in[6];
    const float* b1       = (const float*)d_in[7];
    const float* W2l      = (const float*)d_in[8];
    const float* W2r      = (const float*)d_in[9];
    const float* b2       = (const float*)d_in[10];
    float* out = (float*)d_out;

    const int* src = e_idx;
    const int* dst = e_idx + N_EDGES;

    const size_t HN = (size_t)N_NODES * DIM;       // 6.4M floats
    float* h0     = (float*)d_ws;
    float* h1     = h0 + HN;
    unsigned* aggb= (unsigned*)(h1 + HN);          // N_NODES*64 uints (bf16 agg)
    unsigned* hb0 = aggb + (size_t)N_NODES * 64;   // N_NODES*64 uints
    unsigned* hb1 = hb0 + (size_t)N_NODES * 64;
    int*   nbeg   = (int*)(hb1 + (size_t)N_NODES * 64);
    int*   nend   = nbeg + N_NODES;
    int*   bcount = nend + N_NODES;                // NBUCK
    int*   csr    = bcount + NBUCK;                // NBUCK*CAP
    uintptr_t pa  = ((uintptr_t)(csr + NBUCK * CAP) + 15) & ~(uintptr_t)15;
    uint2* part   = (uint2*)pa;                    // NBUCK*CAP (src, dst&127)
    unsigned short* WfH = (unsigned short*)(part + NBUCK * CAP);  // 2*32768
    unsigned short* WfL = WfH + 2 * 32768;
    float* h2     = h0;                            // h0 dead after layer 1

    build_h0_wf<<<6283, 256, 0, stream>>>(n_id, emb, x_struct, h0, hb0,
                                          W1l, W1r, W2l, W2r, WfH, WfL, bcount);

    // CSR build: 2 kernels, fixed-capacity buckets, no global scan
    part_scatter<<<NPBLK, 256, 0, stream>>>(src, dst, bcount, part);
    bucket_csr<<<NBUCK, 256, 0, stream>>>(part, bcount, nbeg, nend, csr);

    // layer 1
    aggregate_bf16<<<(N_NODES * 64 + 255) / 256, 256, 0, stream>>>(nbeg, nend, csr, hb0, aggb);
    linear_mfma<1, 1><<<(N_NODES + 63) / 64, 256, 0, stream>>>(
        aggb, h0, WfH, WfL, b1, h1, (unsigned short*)hb1);

    // layer 2 (fp32 h2 for edge_dot accuracy margin)
    aggregate_bf16<<<(N_NODES * 64 + 255) / 256, 256, 0, stream>>>(nbeg, nend, csr, hb1, aggb);
    linear_mfma<0, 0><<<(N_NODES + 63) / 64, 256, 0, stream>>>(
        aggb, h1, WfH + 32768, WfL + 32768, b2, h2, nullptr);

    edge_dot<<<(N_LABEL * 32 + 255) / 256, 256, 0, stream>>>(eli, eli + N_LABEL, h2, out);
}

// Round 10
// 249.871 us; speedup vs baseline: 1.1952x; 1.0694x over previous
//
#include <hip/hip_runtime.h>

#define N_NODES 50000
#define DIM     128
#define N_EDGES 800000
#define N_LABEL 200000

// bucket partition: bucket = dst >> 7 (128 nodes/bucket), fixed capacity slots
#define NBUCK 391            // ceil(50000/128)
#define CAP   4096           // slots per bucket (mean fill ~2046, 40-sigma margin)
#define NPBLK 250            // partition blocks
#define CHUNK 3200           // edges per partition block

typedef __attribute__((ext_vector_type(8)))  short short8;    // 8 bf16 (4 VGPRs)
typedef __attribute__((ext_vector_type(16))) float floatx16;  // 32x32 MFMA acc

// split fp32 into bf16 hi + bf16 lo (x ~= hi + lo, rel err ~2^-17), RNE both
__device__ inline void f32_to_bf16x2(float x, unsigned short& hi, unsigned short& lo) {
    unsigned u  = __float_as_uint(x);
    unsigned rh = (u + 0x7FFFu + ((u >> 16) & 1u)) >> 16;
    hi = (unsigned short)rh;
    float hif = __uint_as_float(rh << 16);
    float r = x - hif;
    unsigned ul = __float_as_uint(r);
    unsigned rl = (ul + 0x7FFFu + ((ul >> 16) & 1u)) >> 16;
    lo = (unsigned short)rl;
}

__device__ inline unsigned short f32_to_bf16(float x) {
    unsigned u = __float_as_uint(x);
    return (unsigned short)((u + 0x7FFFu + ((u >> 16) & 1u)) >> 16);
}

__device__ inline unsigned pack_bf16x2(float a, float b) {
    return (unsigned)f32_to_bf16(a) | ((unsigned)f32_to_bf16(b) << 16);
}

__device__ inline float bf_lo(unsigned u) { return __uint_as_float(u << 16); }
__device__ inline float bf_hi(unsigned u) { return __uint_as_float(u & 0xFFFF0000u); }

// fused: blocks [0,6250) build hb0 (bf16 only); [6250,6282) swizzle W; 6282 zeroes bcount
__global__ __launch_bounds__(256)
void build_h0_wf(const int* __restrict__ n_id,
                 const float* __restrict__ emb,
                 const float* __restrict__ xs,
                 unsigned* __restrict__ hb0,
                 const float* __restrict__ W1l, const float* __restrict__ W1r,
                 const float* __restrict__ W2l, const float* __restrict__ W2r,
                 unsigned short* __restrict__ WfH, unsigned short* __restrict__ WfL,
                 int* __restrict__ bcount) {
    if (blockIdx.x < 6250) {
        int t = blockIdx.x * 256 + threadIdx.x;     // < N_NODES*32 exactly
        int i = t >> 5, c = t & 31;
        float4 v;
        if (c < 16) {
            int nid = n_id[i];
            v = ((const float4*)emb)[nid * 16 + c];
        } else {
            v = ((const float4*)xs)[i * 16 + (c - 16)];
        }
        uint2 p;
        p.x = pack_bf16x2(v.x, v.y);
        p.y = pack_bf16x2(v.z, v.w);
        ((uint2*)hb0)[i * 32 + c] = p;
    } else if (blockIdx.x < 6282) {
        int t = (blockIdx.x - 6250) * 256 + threadIdx.x;   // 8192 chunks
        if (t >= 8192) return;
        int L  = t & 63;
        int nt = (t >> 6) & 3;
        int ks = (t >> 8) & 7;
        int p  = (t >> 11) & 1;
        int ly = t >> 12;
        const float* Ws[4] = {W1l, W1r, W2l, W2r};
        const float* W = Ws[ly * 2 + p];
        int n = nt * 32 + (L & 31);
        int kbase = ks * 16 + (L >> 5) * 8;
        short8 hv, lv;
#pragma unroll
        for (int j = 0; j < 8; ++j) {
            unsigned short hh, ll;
            f32_to_bf16x2(W[(kbase + j) * DIM + n], hh, ll);
            hv[j] = (short)hh;
            lv[j] = (short)ll;
        }
        *(short8*)(WfH + (size_t)t * 8) = hv;
        *(short8*)(WfL + (size_t)t * 8) = lv;
    } else {
        for (int i = threadIdx.x; i < NBUCK; i += 256) bcount[i] = 0;
    }
}

// fused hist + range-reserve + grouped scatter (no global scan)
__global__ __launch_bounds__(256)
void part_scatter(const int* __restrict__ src, const int* __restrict__ dst,
                  int* __restrict__ bcount, uint2* __restrict__ part) {
    __shared__ int hist[NBUCK];      // pass1: counts; pass2: write cursors
    int t = threadIdx.x;
    for (int i = t; i < NBUCK; i += 256) hist[i] = 0;
    __syncthreads();
    int base = blockIdx.x * CHUNK;
    for (int e = base + t; e < base + CHUNK; e += 256)
        atomicAdd(&hist[dst[e] >> 7], 1);
    __syncthreads();
    for (int i = t; i < NBUCK; i += 256) {
        int c = hist[i];
        hist[i] = c ? atomicAdd(&bcount[i], c) : 0;   // reserve [base, base+c)
    }
    __syncthreads();
    for (int e = base + t; e < base + CHUNK; e += 256) {
        int d = dst[e];
        int bk = d >> 7;
        int pos = atomicAdd(&hist[bk], 1);
        part[bk * CAP + pos] = make_uint2((unsigned)src[e], (unsigned)(d & 127));
    }
}

// per-bucket: local deg + LDS scan -> nbeg/nend, then localized csr scatter
__global__ __launch_bounds__(256)
void bucket_csr(const uint2* __restrict__ part, const int* __restrict__ bcount,
                int* __restrict__ nbeg, int* __restrict__ nend, int* __restrict__ csr) {
    __shared__ int ldeg[128];
    __shared__ int lcur[128];
    __shared__ int w0s;
    int bk = blockIdx.x;
    int t = threadIdx.x;
    int cnt = bcount[bk];
    int base = bk * CAP;
    if (t < 128) ldeg[t] = 0;
    __syncthreads();
    for (int e = t; e < cnt; e += 256)
        atomicAdd(&ldeg[part[base + e].y], 1);
    __syncthreads();
    int lane = t & 63, wid = t >> 6;
    int v = (t < 128) ? ldeg[t] : 0;
    int s = v;
#pragma unroll
    for (int off = 1; off < 64; off <<= 1) {
        int u = __shfl_up(s, off, 64);
        if (lane >= off) s += u;
    }
    if (t == 63) w0s = s;
    __syncthreads();
    if (t < 128) {
        int excl = s - v + ((wid == 1) ? w0s : 0);
        int node = bk * 128 + t;
        int b0 = base + excl;
        if (node < N_NODES) { nbeg[node] = b0; nend[node] = b0 + v; }
        lcur[t] = b0;
    }
    __syncthreads();
    for (int e = t; e < cnt; e += 256) {
        uint2 p = part[base + e];
        int pos = atomicAdd(&lcur[p.y], 1);
        csr[pos] = (int)p.x;
    }
}

// gather-mean from packed bf16 h; one wave per node, lane holds 2 elems (1 uint).
// Inner loop batched x4 for memory-level parallelism. Output: packed bf16 agg.
__global__ void aggregate_bf16(const int* __restrict__ nbeg, const int* __restrict__ nend,
                               const int* __restrict__ csr_src,
                               const unsigned* __restrict__ hb,
                               unsigned* __restrict__ aggb) {
    int wv   = (blockIdx.x * blockDim.x + threadIdx.x) >> 6;
    int lane = threadIdx.x & 63;
    if (wv >= N_NODES) return;
    int beg = nbeg[wv], end = nend[wv];
    float ax0 = 0.f, ay0 = 0.f, ax1 = 0.f, ay1 = 0.f;
    for (int b = beg; b < end; b += 64) {
        int cnt = min(64, end - b);
        int idx = (b + lane < end) ? csr_src[b + lane] : 0;
        int j = 0;
        for (; j + 4 <= cnt; j += 4) {
            int s0 = __shfl(idx, j,     64);
            int s1 = __shfl(idx, j + 1, 64);
            int s2 = __shfl(idx, j + 2, 64);
            int s3 = __shfl(idx, j + 3, 64);
            unsigned v0 = hb[s0 * 64 + lane];
            unsigned v1 = hb[s1 * 64 + lane];
            unsigned v2 = hb[s2 * 64 + lane];
            unsigned v3 = hb[s3 * 64 + lane];
            ax0 += bf_lo(v0); ay0 += bf_hi(v0);
            ax1 += bf_lo(v1); ay1 += bf_hi(v1);
            ax0 += bf_lo(v2); ay0 += bf_hi(v2);
            ax1 += bf_lo(v3); ay1 += bf_hi(v3);
        }
        for (; j < cnt; ++j) {
            int s = __shfl(idx, j, 64);
            unsigned v = hb[s * 64 + lane];
            ax0 += bf_lo(v); ay0 += bf_hi(v);
        }
    }
    float rd = 1.0f / fmaxf((float)(end - beg), 1.0f);
    aggb[wv * 64 + lane] = pack_bf16x2((ax0 + ax1) * rd, (ay0 + ay1) * rd);
}

// out = relu?( aggb@Wl + hb@Wr + b ); both A terms bf16-exact -> 2 MFMAs each (W hi/lo).
template <int RELU, int WRITE_F32, int WRITE_BF16>
__global__ __launch_bounds__(256)
void linear_mfma(const unsigned* __restrict__ aggb,
                 const unsigned* __restrict__ hbself,
                 const unsigned short* __restrict__ WfH,
                 const unsigned short* __restrict__ WfL,
                 const float* __restrict__ b,
                 float* __restrict__ out,
                 unsigned short* __restrict__ outb) {
    int tid  = threadIdx.x;
    int lane = tid & 63;
    int w    = tid >> 6;
    int row0 = blockIdx.x * 64 + (w & 1) * 32;
    int colhalf = w >> 1;
    int nt0 = colhalf * 2;
    int mc = min(row0 + (lane & 31), N_NODES - 1);
    int kh = lane >> 5;

    floatx16 acc0, acc1;
#pragma unroll
    for (int i = 0; i < 16; ++i) { acc0[i] = 0.f; acc1[i] = 0.f; }

    // A fragment for k-slice ks: bf16 elems ks*16+kh*8 .. +7 = uints ks*8+kh*4 .. +3
    const unsigned* arow = aggb   + (size_t)mc * 64 + kh * 4;
    const unsigned* hrow = hbself + (size_t)mc * 64 + kh * 4;

    // phase 0: agg term
#pragma unroll
    for (int ks = 0; ks < 8; ++ks) {
        short8 aa = *(const short8*)(arow + ks * 8);
        int cbase = (ks * 4 + nt0) * 64 + lane;
        short8 bh0 = *(const short8*)(WfH + (size_t)cbase * 8);
        short8 bl0 = *(const short8*)(WfL + (size_t)cbase * 8);
        short8 bh1 = *(const short8*)(WfH + (size_t)(cbase + 64) * 8);
        short8 bl1 = *(const short8*)(WfL + (size_t)(cbase + 64) * 8);
        acc0 = __builtin_amdgcn_mfma_f32_32x32x16_bf16(aa, bh0, acc0, 0, 0, 0);
        acc0 = __builtin_amdgcn_mfma_f32_32x32x16_bf16(aa, bl0, acc0, 0, 0, 0);
        acc1 = __builtin_amdgcn_mfma_f32_32x32x16_bf16(aa, bh1, acc1, 0, 0, 0);
        acc1 = __builtin_amdgcn_mfma_f32_32x32x16_bf16(aa, bl1, acc1, 0, 0, 0);
    }
    // phase 1: self term
#pragma unroll
    for (int ks = 0; ks < 8; ++ks) {
        short8 aa = *(const short8*)(hrow + ks * 8);
        int cbase = ((8 + ks) * 4 + nt0) * 64 + lane;
        short8 bh0 = *(const short8*)(WfH + (size_t)cbase * 8);
        short8 bl0 = *(const short8*)(WfL + (size_t)cbase * 8);
        short8 bh1 = *(const short8*)(WfH + (size_t)(cbase + 64) * 8);
        short8 bl1 = *(const short8*)(WfL + (size_t)(cbase + 64) * 8);
        acc0 = __builtin_amdgcn_mfma_f32_32x32x16_bf16(aa, bh0, acc0, 0, 0, 0);
        acc0 = __builtin_amdgcn_mfma_f32_32x32x16_bf16(aa, bl0, acc0, 0, 0, 0);
        acc1 = __builtin_amdgcn_mfma_f32_32x32x16_bf16(aa, bh1, acc1, 0, 0, 0);
        acc1 = __builtin_amdgcn_mfma_f32_32x32x16_bf16(aa, bl1, acc1, 0, 0, 0);
    }

    int col0 = colhalf * 64 + (lane & 31);
    float b0 = b[col0], b1 = b[col0 + 32];
#pragma unroll
    for (int reg = 0; reg < 16; ++reg) {
        int rloc = (reg & 3) + 8 * (reg >> 2) + 4 * kh;   // C/D row map (m74/m101)
        int rowg = row0 + rloc;
        if (rowg < N_NODES) {
            float v0 = acc0[reg] + b0;
            float v1 = acc1[reg] + b1;
            if (RELU) { v0 = fmaxf(v0, 0.f); v1 = fmaxf(v1, 0.f); }
            if (WRITE_F32) {
                out[(size_t)rowg * DIM + col0]      = v0;
                out[(size_t)rowg * DIM + col0 + 32] = v1;
            }
            if (WRITE_BF16) {
                outb[(size_t)rowg * DIM + col0]      = f32_to_bf16(v0);
                outb[(size_t)rowg * DIM + col0 + 32] = f32_to_bf16(v1);
            }
        }
    }
}

// logits from fp32 h2; 32 threads/edge + shfl reduce
__global__ void edge_dot(const int* __restrict__ esrc, const int* __restrict__ edst,
                         const float* __restrict__ h2, float* __restrict__ out) {
    int t = blockIdx.x * blockDim.x + threadIdx.x;
    int e = t >> 5, c = t & 31;
    if (e >= N_LABEL) return;
    float4 a  = ((const float4*)h2)[esrc[e] * 32 + c];
    float4 bb = ((const float4*)h2)[edst[e] * 32 + c];
    float p = a.x * bb.x + a.y * bb.y + a.z * bb.z + a.w * bb.w;
#pragma unroll
    for (int off = 16; off; off >>= 1) p += __shfl_down(p, off, 32);
    if (c == 0) out[e] = p;
}

extern "C" void kernel_launch(void* const* d_in, const int* in_sizes, int n_in,
                              void* d_out, int out_size, void* d_ws, size_t ws_size,
                              hipStream_t stream) {
    const int*   n_id     = (const int*)d_in[0];
    const float* x_struct = (const float*)d_in[1];
    const int*   e_idx    = (const int*)d_in[2];   // [2, N_EDGES]
    const int*   eli      = (const int*)d_in[3];   // [2, N_LABEL]
    const float* emb      = (const float*)d_in[4];
    const float* W1l      = (const float*)d_in[5];
    const float* W1r      = (const float*)d_in[6];
    const float* b1       = (const float*)d_in[7];
    const float* W2l      = (const float*)d_in[8];
    const float* W2r      = (const float*)d_in[9];
    const float* b2       = (const float*)d_in[10];
    float* out = (float*)d_out;

    const int* src = e_idx;
    const int* dst = e_idx + N_EDGES;

    const size_t HN = (size_t)N_NODES * DIM;       // 6.4M elems
    float* h2     = (float*)d_ws;                  // fp32 (edge_dot accuracy)
    unsigned* aggb= (unsigned*)(h2 + HN);          // N_NODES*64 uints (bf16 agg)
    unsigned* hb0 = aggb + (size_t)N_NODES * 64;   // bf16 h0
    unsigned* hb1 = hb0 + (size_t)N_NODES * 64;    // bf16 h1
    int*   nbeg   = (int*)(hb1 + (size_t)N_NODES * 64);
    int*   nend   = nbeg + N_NODES;
    int*   bcount = nend + N_NODES;                // NBUCK
    int*   csr    = bcount + NBUCK;                // NBUCK*CAP
    uintptr_t pa  = ((uintptr_t)(csr + NBUCK * CAP) + 15) & ~(uintptr_t)15;
    uint2* part   = (uint2*)pa;                    // NBUCK*CAP (src, dst&127)
    unsigned short* WfH = (unsigned short*)(part + NBUCK * CAP);  // 2*32768
    unsigned short* WfL = WfH + 2 * 32768;

    build_h0_wf<<<6283, 256, 0, stream>>>(n_id, emb, x_struct, hb0,
                                          W1l, W1r, W2l, W2r, WfH, WfL, bcount);

    // CSR build: 2 kernels, fixed-capacity buckets, no global scan
    part_scatter<<<NPBLK, 256, 0, stream>>>(src, dst, bcount, part);
    bucket_csr<<<NBUCK, 256, 0, stream>>>(part, bcount, nbeg, nend, csr);

    // layer 1: bf16 h1 only
    aggregate_bf16<<<(N_NODES * 64 + 255) / 256, 256, 0, stream>>>(nbeg, nend, csr, hb0, aggb);
    linear_mfma<1, 0, 1><<<(N_NODES + 63) / 64, 256, 0, stream>>>(
        aggb, hb0, WfH, WfL, b1, nullptr, (unsigned short*)hb1);

    // layer 2: fp32 h2 only (edge_dot reads fp32 for accuracy margin)
    aggregate_bf16<<<(N_NODES * 64 + 255) / 256, 256, 0, stream>>>(nbeg, nend, csr, hb1, aggb);
    linear_mfma<0, 1, 0><<<(N_NODES + 63) / 64, 256, 0, stream>>>(
        aggb, hb1, WfH + 32768, WfL + 32768, b2, h2, nullptr);

    edge_dot<<<(N_LABEL * 32 + 255) / 256, 256, 0, stream>>>(eli, eli + N_LABEL, h2, out);
}

// Round 12
// 243.201 us; speedup vs baseline: 1.2279x; 1.0274x over previous
//
#include <hip/hip_runtime.h>

#define N_NODES 50000
#define DIM     128
#define N_EDGES 800000
#define N_LABEL 200000

// bucket partition: bucket = dst >> 7 (128 nodes/bucket), fixed capacity slots
#define NBUCK 391            // ceil(50000/128)
#define CAP   4096           // slots per bucket (mean fill ~2046, 40-sigma margin)
#define NPBLK 250            // partition blocks
#define CHUNK 3200           // edges per partition block

typedef __attribute__((ext_vector_type(8)))  short short8;    // 8 bf16 (4 VGPRs)
typedef __attribute__((ext_vector_type(16))) float floatx16;  // 32x32 MFMA acc

// split fp32 into bf16 hi + bf16 lo (x ~= hi + lo, rel err ~2^-17), RNE both
__device__ inline void f32_to_bf16x2(float x, unsigned short& hi, unsigned short& lo) {
    unsigned u  = __float_as_uint(x);
    unsigned rh = (u + 0x7FFFu + ((u >> 16) & 1u)) >> 16;
    hi = (unsigned short)rh;
    float hif = __uint_as_float(rh << 16);
    float r = x - hif;
    unsigned ul = __float_as_uint(r);
    unsigned rl = (ul + 0x7FFFu + ((ul >> 16) & 1u)) >> 16;
    lo = (unsigned short)rl;
}

__device__ inline unsigned short f32_to_bf16(float x) {
    unsigned u = __float_as_uint(x);
    return (unsigned short)((u + 0x7FFFu + ((u >> 16) & 1u)) >> 16);
}

__device__ inline unsigned pack_bf16x2(float a, float b) {
    return (unsigned)f32_to_bf16(a) | ((unsigned)f32_to_bf16(b) << 16);
}

__device__ inline float bf_lo(unsigned u) { return __uint_as_float(u << 16); }
__device__ inline float bf_hi(unsigned u) { return __uint_as_float(u & 0xFFFF0000u); }

// fused: blocks [0,6250) build hb0 (bf16 only); [6250,6282) swizzle W; 6282 zeroes bcount
__global__ __launch_bounds__(256)
void build_h0_wf(const int* __restrict__ n_id,
                 const float* __restrict__ emb,
                 const float* __restrict__ xs,
                 unsigned* __restrict__ hb0,
                 const float* __restrict__ W1l, const float* __restrict__ W1r,
                 const float* __restrict__ W2l, const float* __restrict__ W2r,
                 unsigned short* __restrict__ WfH, unsigned short* __restrict__ WfL,
                 int* __restrict__ bcount) {
    if (blockIdx.x < 6250) {
        int t = blockIdx.x * 256 + threadIdx.x;     // < N_NODES*32 exactly
        int i = t >> 5, c = t & 31;
        float4 v;
        if (c < 16) {
            int nid = n_id[i];
            v = ((const float4*)emb)[nid * 16 + c];
        } else {
            v = ((const float4*)xs)[i * 16 + (c - 16)];
        }
        uint2 p;
        p.x = pack_bf16x2(v.x, v.y);
        p.y = pack_bf16x2(v.z, v.w);
        ((uint2*)hb0)[i * 32 + c] = p;
    } else if (blockIdx.x < 6282) {
        int t = (blockIdx.x - 6250) * 256 + threadIdx.x;   // 8192 chunks
        if (t >= 8192) return;
        int L  = t & 63;
        int nt = (t >> 6) & 3;
        int ks = (t >> 8) & 7;
        int p  = (t >> 11) & 1;
        int ly = t >> 12;
        const float* Ws[4] = {W1l, W1r, W2l, W2r};
        const float* W = Ws[ly * 2 + p];
        int n = nt * 32 + (L & 31);
        int kbase = ks * 16 + (L >> 5) * 8;
        short8 hv, lv;
#pragma unroll
        for (int j = 0; j < 8; ++j) {
            unsigned short hh, ll;
            f32_to_bf16x2(W[(kbase + j) * DIM + n], hh, ll);
            hv[j] = (short)hh;
            lv[j] = (short)ll;
        }
        *(short8*)(WfH + (size_t)t * 8) = hv;
        *(short8*)(WfL + (size_t)t * 8) = lv;
    } else {
        for (int i = threadIdx.x; i < NBUCK; i += 256) bcount[i] = 0;
    }
}

// fused hist + range-reserve + grouped scatter (no global scan)
__global__ __launch_bounds__(256)
void part_scatter(const int* __restrict__ src, const int* __restrict__ dst,
                  int* __restrict__ bcount, uint2* __restrict__ part) {
    __shared__ int hist[NBUCK];      // pass1: counts; pass2: write cursors
    int t = threadIdx.x;
    for (int i = t; i < NBUCK; i += 256) hist[i] = 0;
    __syncthreads();
    int base = blockIdx.x * CHUNK;
    for (int e = base + t; e < base + CHUNK; e += 256)
        atomicAdd(&hist[dst[e] >> 7], 1);
    __syncthreads();
    for (int i = t; i < NBUCK; i += 256) {
        int c = hist[i];
        hist[i] = c ? atomicAdd(&bcount[i], c) : 0;   // reserve [base, base+c)
    }
    __syncthreads();
    for (int e = base + t; e < base + CHUNK; e += 256) {
        int d = dst[e];
        int bk = d >> 7;
        int pos = atomicAdd(&hist[bk], 1);
        part[bk * CAP + pos] = make_uint2((unsigned)src[e], (unsigned)(d & 127));
    }
}

// per-bucket: local deg + LDS scan -> nbeg/nend, then localized csr scatter
__global__ __launch_bounds__(256)
void bucket_csr(const uint2* __restrict__ part, const int* __restrict__ bcount,
                int* __restrict__ nbeg, int* __restrict__ nend, int* __restrict__ csr) {
    __shared__ int ldeg[128];
    __shared__ int lcur[128];
    __shared__ int w0s;
    int bk = blockIdx.x;
    int t = threadIdx.x;
    int cnt = bcount[bk];
    int base = bk * CAP;
    if (t < 128) ldeg[t] = 0;
    __syncthreads();
    for (int e = t; e < cnt; e += 256)
        atomicAdd(&ldeg[part[base + e].y], 1);
    __syncthreads();
    int lane = t & 63, wid = t >> 6;
    int v = (t < 128) ? ldeg[t] : 0;
    int s = v;
#pragma unroll
    for (int off = 1; off < 64; off <<= 1) {
        int u = __shfl_up(s, off, 64);
        if (lane >= off) s += u;
    }
    if (t == 63) w0s = s;
    __syncthreads();
    if (t < 128) {
        int excl = s - v + ((wid == 1) ? w0s : 0);
        int node = bk * 128 + t;
        int b0 = base + excl;
        if (node < N_NODES) { nbeg[node] = b0; nend[node] = b0 + v; }
        lcur[t] = b0;
    }
    __syncthreads();
    for (int e = t; e < cnt; e += 256) {
        uint2 p = part[base + e];
        int pos = atomicAdd(&lcur[p.y], 1);
        csr[pos] = (int)p.x;
    }
}

// gather-mean from packed bf16 h; one wave per node, lane holds 2 elems (1 uint).
// Inner loop batched x8 for memory-level parallelism. Output: packed bf16 agg (MEAN!).
__global__ void aggregate_bf16(const int* __restrict__ nbeg, const int* __restrict__ nend,
                               const int* __restrict__ csr_src,
                               const unsigned* __restrict__ hb,
                               unsigned* __restrict__ aggb) {
    int wv   = (blockIdx.x * blockDim.x + threadIdx.x) >> 6;
    int lane = threadIdx.x & 63;
    if (wv >= N_NODES) return;
    int beg = nbeg[wv], end = nend[wv];
    float ax0 = 0.f, ay0 = 0.f, ax1 = 0.f, ay1 = 0.f;
    float ax2 = 0.f, ay2 = 0.f, ax3 = 0.f, ay3 = 0.f;
    for (int b = beg; b < end; b += 64) {
        int cnt = min(64, end - b);
        int idx = (b + lane < end) ? csr_src[b + lane] : 0;
        int j = 0;
        for (; j + 8 <= cnt; j += 8) {
            int s0 = __shfl(idx, j,     64);
            int s1 = __shfl(idx, j + 1, 64);
            int s2 = __shfl(idx, j + 2, 64);
            int s3 = __shfl(idx, j + 3, 64);
            int s4 = __shfl(idx, j + 4, 64);
            int s5 = __shfl(idx, j + 5, 64);
            int s6 = __shfl(idx, j + 6, 64);
            int s7 = __shfl(idx, j + 7, 64);
            unsigned v0 = hb[s0 * 64 + lane];
            unsigned v1 = hb[s1 * 64 + lane];
            unsigned v2 = hb[s2 * 64 + lane];
            unsigned v3 = hb[s3 * 64 + lane];
            unsigned v4 = hb[s4 * 64 + lane];
            unsigned v5 = hb[s5 * 64 + lane];
            unsigned v6 = hb[s6 * 64 + lane];
            unsigned v7 = hb[s7 * 64 + lane];
            ax0 += bf_lo(v0); ay0 += bf_hi(v0);
            ax1 += bf_lo(v1); ay1 += bf_hi(v1);
            ax2 += bf_lo(v2); ay2 += bf_hi(v2);
            ax3 += bf_lo(v3); ay3 += bf_hi(v3);
            ax0 += bf_lo(v4); ay0 += bf_hi(v4);
            ax1 += bf_lo(v5); ay1 += bf_hi(v5);
            ax2 += bf_lo(v6); ay2 += bf_hi(v6);
            ax3 += bf_lo(v7); ay3 += bf_hi(v7);
        }
        for (; j + 2 <= cnt; j += 2) {
            int s0 = __shfl(idx, j,     64);
            int s1 = __shfl(idx, j + 1, 64);
            unsigned v0 = hb[s0 * 64 + lane];
            unsigned v1 = hb[s1 * 64 + lane];
            ax0 += bf_lo(v0); ay0 += bf_hi(v0);
            ax1 += bf_lo(v1); ay1 += bf_hi(v1);
        }
        if (j < cnt) {
            int s = __shfl(idx, j, 64);
            unsigned v = hb[s * 64 + lane];
            ax0 += bf_lo(v); ay0 += bf_hi(v);
        }
    }
    float rd = 1.0f / fmaxf((float)(end - beg), 1.0f);
    aggb[wv * 64 + lane] =
        pack_bf16x2(((ax0 + ax1) + (ax2 + ax3)) * rd,
                    ((ay0 + ay1) + (ay2 + ay3)) * rd);
}

// out = relu?( aggb@Wl + hb@Wr + b ); both A terms bf16-exact -> 2 MFMAs each (W hi/lo).
template <int RELU, int WRITE_F32, int WRITE_BF16>
__global__ __launch_bounds__(256)
void linear_mfma(const unsigned* __restrict__ aggb,
                 const unsigned* __restrict__ hbself,
                 const unsigned short* __restrict__ WfH,
                 const unsigned short* __restrict__ WfL,
                 const float* __restrict__ b,
                 float* __restrict__ out,
                 unsigned short* __restrict__ outb) {
    int tid  = threadIdx.x;
    int lane = tid & 63;
    int w    = tid >> 6;
    int row0 = blockIdx.x * 64 + (w & 1) * 32;
    int colhalf = w >> 1;
    int nt0 = colhalf * 2;
    int mc = min(row0 + (lane & 31), N_NODES - 1);
    int kh = lane >> 5;

    floatx16 acc0, acc1;
#pragma unroll
    for (int i = 0; i < 16; ++i) { acc0[i] = 0.f; acc1[i] = 0.f; }

    // A fragment for k-slice ks: bf16 elems ks*16+kh*8 .. +7 = uints ks*8+kh*4 .. +3
    const unsigned* arow = aggb   + (size_t)mc * 64 + kh * 4;
    const unsigned* hrow = hbself + (size_t)mc * 64 + kh * 4;

    // phase 0: agg term
#pragma unroll
    for (int ks = 0; ks < 8; ++ks) {
        short8 aa = *(const short8*)(arow + ks * 8);
        int cbase = (ks * 4 + nt0) * 64 + lane;
        short8 bh0 = *(const short8*)(WfH + (size_t)cbase * 8);
        short8 bl0 = *(const short8*)(WfL + (size_t)cbase * 8);
        short8 bh1 = *(const short8*)(WfH + (size_t)(cbase + 64) * 8);
        short8 bl1 = *(const short8*)(WfL + (size_t)(cbase + 64) * 8);
        acc0 = __builtin_amdgcn_mfma_f32_32x32x16_bf16(aa, bh0, acc0, 0, 0, 0);
        acc0 = __builtin_amdgcn_mfma_f32_32x32x16_bf16(aa, bl0, acc0, 0, 0, 0);
        acc1 = __builtin_amdgcn_mfma_f32_32x32x16_bf16(aa, bh1, acc1, 0, 0, 0);
        acc1 = __builtin_amdgcn_mfma_f32_32x32x16_bf16(aa, bl1, acc1, 0, 0, 0);
    }
    // phase 1: self term
#pragma unroll
    for (int ks = 0; ks < 8; ++ks) {
        short8 aa = *(const short8*)(hrow + ks * 8);
        int cbase = ((8 + ks) * 4 + nt0) * 64 + lane;
        short8 bh0 = *(const short8*)(WfH + (size_t)cbase * 8);
        short8 bl0 = *(const short8*)(WfL + (size_t)cbase * 8);
        short8 bh1 = *(const short8*)(WfH + (size_t)(cbase + 64) * 8);
        short8 bl1 = *(const short8*)(WfL + (size_t)(cbase + 64) * 8);
        acc0 = __builtin_amdgcn_mfma_f32_32x32x16_bf16(aa, bh0, acc0, 0, 0, 0);
        acc0 = __builtin_amdgcn_mfma_f32_32x32x16_bf16(aa, bl0, acc0, 0, 0, 0);
        acc1 = __builtin_amdgcn_mfma_f32_32x32x16_bf16(aa, bh1, acc1, 0, 0, 0);
        acc1 = __builtin_amdgcn_mfma_f32_32x32x16_bf16(aa, bl1, acc1, 0, 0, 0);
    }

    int col0 = colhalf * 64 + (lane & 31);
    float b0 = b[col0], b1 = b[col0 + 32];
#pragma unroll
    for (int reg = 0; reg < 16; ++reg) {
        int rloc = (reg & 3) + 8 * (reg >> 2) + 4 * kh;   // C/D row map (m74/m101)
        int rowg = row0 + rloc;
        if (rowg < N_NODES) {
            float v0 = acc0[reg] + b0;
            float v1 = acc1[reg] + b1;
            if (RELU) { v0 = fmaxf(v0, 0.f); v1 = fmaxf(v1, 0.f); }
            if (WRITE_F32) {
                out[(size_t)rowg * DIM + col0]      = v0;
                out[(size_t)rowg * DIM + col0 + 32] = v1;
            }
            if (WRITE_BF16) {
                outb[(size_t)rowg * DIM + col0]      = f32_to_bf16(v0);
                outb[(size_t)rowg * DIM + col0 + 32] = f32_to_bf16(v1);
            }
        }
    }
}

// logits from fp32 h2; 16 lanes/edge, 2xfloat4 per endpoint row (4 edges/wave, 8 loads in flight)
__global__ void edge_dot(const int* __restrict__ esrc, const int* __restrict__ edst,
                         const float* __restrict__ h2, float* __restrict__ out) {
    int t = blockIdx.x * blockDim.x + threadIdx.x;
    int e = t >> 4, c = t & 15;
    if (e >= N_LABEL) return;
    const float4* H = (const float4*)h2;
    int rs = esrc[e], rd = edst[e];
    float4 a0 = H[rs * 32 + 2 * c];
    float4 a1 = H[rs * 32 + 2 * c + 1];
    float4 b0 = H[rd * 32 + 2 * c];
    float4 b1 = H[rd * 32 + 2 * c + 1];
    float p = a0.x * b0.x + a0.y * b0.y + a0.z * b0.z + a0.w * b0.w
            + a1.x * b1.x + a1.y * b1.y + a1.z * b1.z + a1.w * b1.w;
#pragma unroll
    for (int off = 8; off; off >>= 1) p += __shfl_down(p, off, 16);
    if (c == 0) out[e] = p;
}

extern "C" void kernel_launch(void* const* d_in, const int* in_sizes, int n_in,
                              void* d_out, int out_size, void* d_ws, size_t ws_size,
                              hipStream_t stream) {
    const int*   n_id     = (const int*)d_in[0];
    const float* x_struct = (const float*)d_in[1];
    const int*   e_idx    = (const int*)d_in[2];   // [2, N_EDGES]
    const int*   eli      = (const int*)d_in[3];   // [2, N_LABEL]
    const float* emb      = (const float*)d_in[4];
    const float* W1l      = (const float*)d_in[5];
    const float* W1r      = (const float*)d_in[6];
    const float* b1       = (const float*)d_in[7];
    const float* W2l      = (const float*)d_in[8];
    const float* W2r      = (const float*)d_in[9];
    const float* b2       = (const float*)d_in[10];
    float* out = (float*)d_out;

    const int* src = e_idx;
    const int* dst = e_idx + N_EDGES;

    const size_t HN = (size_t)N_NODES * DIM;       // 6.4M elems
    float* h2     = (float*)d_ws;                  // fp32 (edge_dot accuracy)
    unsigned* aggb= (unsigned*)(h2 + HN);          // N_NODES*64 uints (bf16 agg)
    unsigned* hb0 = aggb + (size_t)N_NODES * 64;   // bf16 h0
    unsigned* hb1 = hb0 + (size_t)N_NODES * 64;    // bf16 h1
    int*   nbeg   = (int*)(hb1 + (size_t)N_NODES * 64);
    int*   nend   = nbeg + N_NODES;
    int*   bcount = nend + N_NODES;                // NBUCK
    int*   csr    = bcount + NBUCK;                // NBUCK*CAP
    uintptr_t pa  = ((uintptr_t)(csr + NBUCK * CAP) + 15) & ~(uintptr_t)15;
    uint2* part   = (uint2*)pa;                    // NBUCK*CAP (src, dst&127)
    unsigned short* WfH = (unsigned short*)(part + NBUCK * CAP);  // 2*32768
    unsigned short* WfL = WfH + 2 * 32768;

    build_h0_wf<<<6283, 256, 0, stream>>>(n_id, emb, x_struct, hb0,
                                          W1l, W1r, W2l, W2r, WfH, WfL, bcount);

    // CSR build: 2 kernels, fixed-capacity buckets, no global scan
    part_scatter<<<NPBLK, 256, 0, stream>>>(src, dst, bcount, part);
    bucket_csr<<<NBUCK, 256, 0, stream>>>(part, bcount, nbeg, nend, csr);

    // layer 1: bf16 h1 only
    aggregate_bf16<<<(N_NODES * 64 + 255) / 256, 256, 0, stream>>>(nbeg, nend, csr, hb0, aggb);
    linear_mfma<1, 0, 1><<<(N_NODES + 63) / 64, 256, 0, stream>>>(
        aggb, hb0, WfH, WfL, b1, nullptr, (unsigned short*)hb1);

    // layer 2: fp32 h2 only (edge_dot reads fp32 for accuracy margin)
    aggregate_bf16<<<(N_NODES * 64 + 255) / 256, 256, 0, stream>>>(nbeg, nend, csr, hb1, aggb);
    linear_mfma<0, 1, 0><<<(N_NODES + 63) / 64, 256, 0, stream>>>(
        aggb, hb1, WfH + 32768, WfL + 32768, b2, h2, nullptr);

    edge_dot<<<(N_LABEL * 16 + 255) / 256, 256, 0, stream>>>(eli, eli + N_LABEL, h2, out);
}